// Round 10
// baseline (115.040 us; speedup 1.0000x reference)
//
#include <hip/hip_runtime.h>
#include <hip/hip_bf16.h>

#define I_N 16
#define C_N 32
#define L_N 32
#define R_N 36
#define D_N 1024
#define EPSF 1e-8f

typedef _Float16 f16;
typedef __attribute__((ext_vector_type(8))) _Float16 half8;
typedef __attribute__((ext_vector_type(4))) float floatx4;

// async global->LDS, 16B per lane; LDS dest = wave-uniform base + lane*16
__device__ __forceinline__ void gl16(const f16* g, f16* l) {
  __builtin_amdgcn_global_load_lds(
      (const __attribute__((address_space(1))) void*)g,
      (__attribute__((address_space(3))) void*)l, 16, 0, 0);
}

// ---------------- block-wide sum over 256 threads ----------------
__device__ __forceinline__ float blk_sum_256(float v, float* red) {
  #pragma unroll
  for (int off = 32; off > 0; off >>= 1) v += __shfl_down(v, off, 64);
  int wid = threadIdx.x >> 6;
  if ((threadIdx.x & 63) == 0) red[wid] = v;
  __syncthreads();
  float s = red[0] + red[1] + red[2] + red[3];
  __syncthreads();
  return s;
}

// ---------------- K1: Dim_learned_weights rows + f16 copy ----------------
// idx = floor(linspace(0,D,D)) clipped == identity -> weights = sigmoid(W)
__global__ __launch_bounds__(256) void k_dlw(const float* __restrict__ W,
    const float* __restrict__ simw, const float* __restrict__ tlw,
    float* __restrict__ Dlw, f16* __restrict__ DlwH) {
  int row = blockIdx.x, tid = threadIdx.x;
  __shared__ float red[4];
  const float* Wr = W + (size_t)row * D_N;
  float w[4]; float p = 0.f;
  #pragma unroll
  for (int k = 0; k < 4; ++k) {
    int j = tid + k * 256;
    float x = Wr[j];
    w[k] = 1.f / (1.f + expf(-x));
    p += w[k];
  }
  float S = blk_sum_256(p, red);
  float mean = S * (1.f / 1024.f);
  p = 0.f;
  #pragma unroll
  for (int k = 0; k < 4; ++k) { float d = w[k] - mean; p += d * d; }
  float S2 = blk_sum_256(p, red);
  float stdv = sqrtf(S2 * (1.f / 1023.f));   // ddof=1
  float thres = mean + simw[row] * stdv;
  float eT = expf(tlw[0]);
  float mw[4]; p = 0.f;
  #pragma unroll
  for (int k = 0; k < 4; ++k) {
    float val = eT * (w[k] - thres);
    float mp = tanhf(expf(val));
    mw[k] = mp * w[k];
    p += mw[k] * mw[k];
  }
  float S3 = blk_sum_256(p, red);
  float inv = 1.f / (sqrtf(S3) + EPSF);
  #pragma unroll
  for (int k = 0; k < 4; ++k) {
    int j = tid + k * 256;
    float v = mw[k] * inv;
    Dlw[(size_t)row * D_N + j] = v;
    DlwH[(size_t)row * D_N + j] = (f16)v;
  }
}

// ---------------- K2a: partial column sums of Dlw (64-row strips) ----------------
__global__ __launch_bounds__(256) void k_diag_part(const float* __restrict__ Dlw,
                                                   float* __restrict__ dpart) {
  int col = blockIdx.x * 256 + threadIdx.x;
  int p = blockIdx.y;                 // 0..15
  float s = 0.f;
  #pragma unroll 8
  for (int r = p * 64; r < p * 64 + 64; ++r) s += Dlw[(size_t)r * D_N + col];
  dpart[(size_t)p * D_N + col] = s;
}

// ---------------- K2b: fold partials -> diag, + prefix scan of cap_lens ----------------
// blocks 0..3: diag columns; block 4: pfx[c], mp = 16*sum(lens)
__global__ __launch_bounds__(256) void k_diag2p(const float* __restrict__ dpart,
    const int* __restrict__ lens, float* __restrict__ diag,
    int* __restrict__ pfx, int* __restrict__ mp) {
  if (blockIdx.x < 4) {
    int col = blockIdx.x * 256 + threadIdx.x;
    float s = 0.f;
    #pragma unroll
    for (int p = 0; p < 16; ++p) s += dpart[(size_t)p * D_N + col];
    diag[col] = s;
  } else if (threadIdx.x < 64) {
    int l = threadIdx.x;
    int v = (l < 32) ? lens[l] : 0;
    int s = v;
    #pragma unroll
    for (int off = 1; off < 32; off <<= 1) {
      int t = __shfl_up(s, off, 64);
      if (l >= off) s += t;
    }
    if (l < 32) pfx[l] = s - v;          // exclusive prefix
    if (l == 31) { pfx[32] = s; mp[0] = s * 16; }
  }
}

// ---------------- fused prep: cap->f16 | img->f16 | img*diag->f16 (padded 48) ----------------
__global__ __launch_bounds__(256) void k_prep(const float* __restrict__ cap,
    const float* __restrict__ img, const float* __restrict__ diag,
    f16* __restrict__ capH, f16* __restrict__ imgH, f16* __restrict__ imgdH) {
  int bid = blockIdx.x;
  if (bid < 1024) {
    size_t base = (size_t)bid * D_N;
    #pragma unroll
    for (int k = 0; k < 4; ++k) {
      int j = threadIdx.x + k * 256;
      capH[base + j] = (f16)cap[base + j];
    }
  } else if (bid < 1600) {
    size_t base = (size_t)(bid - 1024) * D_N;
    #pragma unroll
    for (int k = 0; k < 4; ++k) {
      int j = threadIdx.x + k * 256;
      imgH[base + j] = (f16)img[base + j];
    }
  } else {
    int row = bid - 1600;            // 0..767 = i*48 + r
    int i = row / 48, r = row % 48;
    size_t dst = (size_t)row * D_N;
    if (r < R_N) {
      size_t src = ((size_t)i * R_N + r) * D_N;
      #pragma unroll
      for (int k = 0; k < 4; ++k) {
        int j = threadIdx.x + k * 256;
        imgdH[dst + j] = (f16)(img[src + j] * diag[j]);
      }
    } else {
      #pragma unroll
      for (int k = 0; k < 4; ++k) {
        int j = threadIdx.x + k * 256;
        imgdH[dst + j] = (f16)0.f;
      }
    }
  }
}

// ---------------- K3: qk[m=(c,l)][i*48+n] = cap . (img*diag)  (MFMA f16) ----------------
// XOR-involution swizzle on BOTH ds_write and ds_read offsets (row bits 1..5 kept).
__global__ __launch_bounds__(256) void k_qk(const f16* __restrict__ A,
    const f16* __restrict__ B, float* __restrict__ qk) {
  int mt = blockIdx.x;             // 0..15
  int i  = blockIdx.y;             // 0..15
  int tid = threadIdx.x;
  int w = tid >> 6, lane = tid & 63;
  int l15 = lane & 15, h = lane >> 4;
  __shared__ __align__(16) f16 Als[64 * 32];
  __shared__ __align__(16) f16 Bls[48 * 32];
  floatx4 acc[3];
  #pragma unroll
  for (int nf = 0; nf < 3; ++nf) acc[nf] = (floatx4)0.f;
  int arow = tid >> 2;             // 0..63
  int u = tid & 3;                 // 16B unit within row
  int vf = (u | ((arow & 1) << 2)) ^ ((arow >> 1) & 7);
  int wofs = (((arow & 62) | (vf >> 2)) * 32) + (vf & 3) * 8;
  const f16* Ag = A + (size_t)(mt * 64 + arow) * D_N + u * 8;
  const f16* Bg = B + (size_t)(i * 48 + arow) * D_N + u * 8;
  int v2 = (h | ((l15 & 1) << 2)) ^ ((l15 >> 1) & 7);
  int rbit = (v2 >> 2) & 1;
  int pun = (v2 & 3) * 8;
  int aoff = (w * 16 + (l15 & 14) + rbit) * 32 + pun;
  int boff[3];
  #pragma unroll
  for (int nf = 0; nf < 3; ++nf) boff[nf] = (nf * 16 + (l15 & 14) + rbit) * 32 + pun;
  for (int kk = 0; kk < D_N; kk += 32) {
    *(float4*)(&Als[wofs]) = *(const float4*)(Ag + kk);
    if (tid < 192) *(float4*)(&Bls[wofs]) = *(const float4*)(Bg + kk);
    __syncthreads();
    half8 a = *(const half8*)(&Als[aoff]);
    #pragma unroll
    for (int nf = 0; nf < 3; ++nf) {
      half8 b = *(const half8*)(&Bls[boff[nf]]);
      acc[nf] = __builtin_amdgcn_mfma_f32_16x16x32_f16(a, b, acc[nf], 0, 0, 0);
    }
    __syncthreads();
  }
  #pragma unroll
  for (int nf = 0; nf < 3; ++nf)
    #pragma unroll
    for (int j = 0; j < 4; ++j) {
      int m = mt * 64 + w * 16 + h * 4 + j;
      int n = nf * 16 + l15;
      qk[(size_t)m * 768 + i * 48 + n] = acc[nf][j];
    }
}

// ---------------- K4: tanh/leaky/mask -> l2norm over words -> softmax over regions ----------------
__global__ __launch_bounds__(256) void k_attnsm(const float* __restrict__ qk,
    const int* __restrict__ lens, const float* __restrict__ tsw,
    float* __restrict__ pw) {
  int c = blockIdx.x >> 4, i = blockIdx.x & 15;
  int tid = threadIdx.x;
  int len = lens[c];
  float smooth = expf(tsw[0]);
  __shared__ float att[L_N][R_N];
  __shared__ float cn[R_N];
  for (int e = tid; e < L_N * R_N; e += 256) {
    int l = e / R_N, r = e % R_N;
    float x = qk[(size_t)(c * 32 + l) * 768 + i * 48 + r];
    float t = tanhf(x);
    float v = (t >= 0.f) ? t : 0.1f * t;   // LeakyReLU(0.1)
    if (l >= len) v = 0.f;                 // word mask
    att[l][r] = v;
  }
  __syncthreads();
  if (tid < R_N) {                          // l2norm over word dim
    float s = 0.f;
    #pragma unroll
    for (int l = 0; l < L_N; ++l) s += att[l][tid] * att[l][tid];
    cn[tid] = sqrtf(s) + EPSF;
  }
  __syncthreads();
  if (tid < L_N) {                          // softmax over regions
    float z[R_N];
    float mx = -3.4e38f;
    #pragma unroll
    for (int r = 0; r < R_N; ++r) { z[r] = att[tid][r] / cn[r] * smooth; mx = fmaxf(mx, z[r]); }
    float se = 0.f;
    #pragma unroll
    for (int r = 0; r < R_N; ++r) { float e = expf(z[r] - mx); z[r] = e; se += e; }
    float inv = 1.f / se;
    #pragma unroll
    for (int r = 0; r < R_N; ++r) att[tid][r] = z[r] * inv;
  }
  __syncthreads();
  for (int e = tid; e < L_N * R_N; e += 256) {
    int l = e / R_N, r = e % R_N;
    pw[((size_t)i * 1024 + c * 32 + l) * R_N + r] = att[l][r];
  }
}

// ---------------- K5: ctx = attn @ img[i]; l2norm; * cap -> COMPACT sim_loc (f16) ----------------
// One block per (caption, image): stage img[i] ONCE (72 KB), two 16-row sub-passes.
// 512 blocks = exactly 2/CU, single residency round.
__global__ __launch_bounds__(256) void k_ctx(const float* __restrict__ pw,
    const f16* __restrict__ imgH, const float* __restrict__ cap,
    const int* __restrict__ lens, const int* __restrict__ pfx,
    f16* __restrict__ slc) {
  int c  = blockIdx.x;             // 0..31 caption
  int i  = blockIdx.y;             // 0..15 image
  int tid = threadIdx.x;
  int w = tid >> 6;                // wave id
  int cg = tid & 63;
  int len = lens[c];
  int pf = pfx[c];
  __shared__ float pA[32][R_N];
  __shared__ __align__(16) f16 rows[R_N][1024];   // 72 KB
  for (int e = tid; e < 32 * R_N; e += 256) {
    int rr = e / R_N, r = e % R_N;
    pA[rr][r] = pw[((size_t)i * 1024 + c * 32 + rr) * R_N + r];
  }
  const f16* base = imgH + (size_t)i * R_N * D_N;
  #pragma unroll
  for (int t = 0; t < 9; ++t) {
    int rr = w * 9 + t;
    const f16* src = base + (size_t)rr * D_N + cg * 8;
    gl16(src,       &rows[rr][0]);
    gl16(src + 512, &rows[rr][512]);
  }
  __syncthreads();                 // drains vmcnt + lgkm once
  int d0 = cg * 8, d1 = 512 + cg * 8;
  #pragma unroll
  for (int sub = 0; sub < 2; ++sub) {
    float acc[4][16];
    #pragma unroll
    for (int j = 0; j < 4; ++j)
      #pragma unroll
      for (int q = 0; q < 16; ++q) acc[j][q] = 0.f;
    for (int k = 0; k < R_N; ++k) {
      half8 h0 = *(const half8*)(&rows[k][d0]);
      half8 h1 = *(const half8*)(&rows[k][d1]);
      float bv[16];
      #pragma unroll
      for (int q = 0; q < 8; ++q) { bv[q] = (float)h0[q]; bv[8 + q] = (float)h1[q]; }
      #pragma unroll
      for (int j = 0; j < 4; ++j) {
        float a = pA[sub * 16 + w * 4 + j][k];
        #pragma unroll
        for (int q = 0; q < 16; ++q) acc[j][q] += a * bv[q];
      }
    }
    #pragma unroll
    for (int j = 0; j < 4; ++j) {
      int l = sub * 16 + w * 4 + j;      // word index 0..31
      float ss = 0.f;
      #pragma unroll
      for (int q = 0; q < 16; ++q) ss += acc[j][q] * acc[j][q];
      #pragma unroll
      for (int off = 1; off < 64; off <<= 1) ss += __shfl_xor(ss, off, 64);
      if (l < len) {
        float inv = 1.f / (sqrtf(ss) + EPSF);
        const float* capr = cap + ((size_t)c * L_N + l) * D_N;
        float4 c0 = *(const float4*)(capr + d0);
        float4 c1 = *(const float4*)(capr + d0 + 4);
        float4 c2 = *(const float4*)(capr + d1);
        float4 c3 = *(const float4*)(capr + d1 + 4);
        float cv[16] = {c0.x,c0.y,c0.z,c0.w, c1.x,c1.y,c1.z,c1.w,
                        c2.x,c2.y,c2.z,c2.w, c3.x,c3.y,c3.z,c3.w};
        union { f16 h[16]; float4 f4[2]; } u;
        #pragma unroll
        for (int q = 0; q < 16; ++q) u.h[q] = (f16)(acc[j][q] * inv * cv[q]);
        f16* dst = slc + ((size_t)((pf + l) * 16 + i)) * D_N;
        *(float4*)(dst + d0) = u.f4[0];
        *(float4*)(dst + d1) = u.f4[1];
      }
    }
  }
}

// ---------------- K6: big GEMM (compacted M) f16 MFMA, fused rowsum/rowsumsq ----------------
// 128x128 tile, BK=32, 4 waves 2x2. TWO-buffer LDS (32 KB -> 5 blocks/CU, whole
// grid resident), depth-1 prefetch, counted vmcnt(4). sched_barrier(0) on BOTH
// sides of COMPUTE pins its ds_reads between the barriers (rule #18).
__global__ __launch_bounds__(256) void k_gemm(const f16* __restrict__ A,
    const f16* __restrict__ B, const int* __restrict__ mp,
    float* __restrict__ rs16, float* __restrict__ rq16) {
  int bx = blockIdx.x, by = blockIdx.y;
  int Mp = mp[0];
  int m0 = bx * 128, n0 = by * 128;
  if (m0 >= Mp) return;            // uniform per block; compacted tail
  int tid = threadIdx.x;
  int w = tid >> 6, lane = tid & 63;
  int l15 = lane & 15, h = lane >> 4;
  int wm = w >> 1, wn = w & 1;
  __shared__ __align__(16) f16 AB[2][2][128 * 32];   // 32 KB
  floatx4 acc[4][4];
  #pragma unroll
  for (int mf = 0; mf < 4; ++mf)
    #pragma unroll
    for (int nf = 0; nf < 4; ++nf) acc[mf][nf] = (floatx4)0.f;

  // ---- staging: lane's linear LDS slot (r_p,u_p) must receive logical (r_l,u_l)
  int r_p = lane >> 2, u_p = lane & 3;
  int sw = (r_p >> 1) & 7;
  int val = (u_p | ((r_p & 1) << 2)) ^ sw;
  int r_l = (r_p & 14) | (val >> 2);
  int u_l = val & 3;
  const f16* As0 = A + (size_t)(m0 + w * 32 +  0 + r_l) * D_N + u_l * 8;
  const f16* As1 = A + (size_t)(m0 + w * 32 + 16 + r_l) * D_N + u_l * 8;
  const f16* Bs0 = B + (size_t)(n0 + w * 32 +  0 + r_l) * D_N + u_l * 8;
  const f16* Bs1 = B + (size_t)(n0 + w * 32 + 16 + r_l) * D_N + u_l * 8;

  // ---- fragment reads: physical (swizzled) offsets, loop-invariant
  int v2 = (h | ((l15 & 1) << 2)) ^ ((l15 >> 1) & 7);
  int rbit = (v2 >> 2) & 1;
  int pun = (v2 & 3) * 8;
  int aoff[4], boff[4];
  #pragma unroll
  for (int f = 0; f < 4; ++f) {
    aoff[f] = (wm * 64 + f * 16 + (l15 & 14) + rbit) * 32 + pun;
    boff[f] = (wn * 64 + f * 16 + (l15 & 14) + rbit) * 32 + pun;
  }

  #define STAGE(kt, b) { \
    int kof = (kt) * 32; \
    gl16(As0 + kof, &AB[b][0][(w * 32 +  0) * 32]); \
    gl16(As1 + kof, &AB[b][0][(w * 32 + 16) * 32]); \
    gl16(Bs0 + kof, &AB[b][1][(w * 32 +  0) * 32]); \
    gl16(Bs1 + kof, &AB[b][1][(w * 32 + 16) * 32]); }

  #define COMPUTE(b) { \
    half8 af[4], bf[4]; \
    _Pragma("unroll") for (int f = 0; f < 4; ++f) af[f] = *(const half8*)(&AB[b][0][aoff[f]]); \
    _Pragma("unroll") for (int f = 0; f < 4; ++f) bf[f] = *(const half8*)(&AB[b][1][boff[f]]); \
    _Pragma("unroll") for (int mf = 0; mf < 4; ++mf) \
      _Pragma("unroll") for (int nf = 0; nf < 4; ++nf) \
        acc[mf][nf] = __builtin_amdgcn_mfma_f32_16x16x32_f16(af[mf], bf[nf], acc[mf][nf], 0, 0, 0); }

  STAGE(0, 0);
  for (int kk = 0; kk < 31; ++kk) {
    STAGE(kk + 1, (kk + 1) & 1);
    asm volatile("s_waitcnt vmcnt(4)" ::: "memory");  // tile kk's 4 loads done
    __builtin_amdgcn_s_barrier();
    __builtin_amdgcn_sched_barrier(0);
    COMPUTE(kk & 1);
    __builtin_amdgcn_sched_barrier(0);                // pin reads before barrier
    __builtin_amdgcn_s_barrier();                     // all reads of buf done
  }
  asm volatile("s_waitcnt vmcnt(0)" ::: "memory");
  __builtin_amdgcn_s_barrier();
  __builtin_amdgcn_sched_barrier(0);
  COMPUTE(1);
  #undef STAGE
  #undef COMPUTE

  int slot = by * 2 + wn;          // 0..15, deterministic partials (no atomics)
  #pragma unroll
  for (int mf = 0; mf < 4; ++mf)
    #pragma unroll
    for (int j = 0; j < 4; ++j) {
      float s = 0.f, q = 0.f;
      #pragma unroll
      for (int nf = 0; nf < 4; ++nf) { float v = acc[mf][nf][j]; s += v; q += v * v; }
      #pragma unroll
      for (int off = 1; off < 16; off <<= 1) { s += __shfl_xor(s, off, 64); q += __shfl_xor(q, off, 64); }
      if (l15 == 0) {
        int m = m0 + wm * 64 + mf * 16 + h * 4 + j;
        rs16[(size_t)slot * 16384 + m] = s;
        rq16[(size_t)slot * 16384 + m] = q;
      }
    }
}

// ---------------- K7: sim[i][c] — one block per (i,c), lane per word (compact rows) ----------------
__global__ __launch_bounds__(64) void k_final(const float* __restrict__ rs16,
    const float* __restrict__ rq16, const int* __restrict__ lens,
    const int* __restrict__ pfx, float* __restrict__ out) {
  int b = blockIdx.x;              // 0..511 = i*32 + c
  int c = b & 31;
  int l = threadIdx.x;             // 0..63, words are 0..31
  int len = lens[c];
  float sv = 0.f;
  if (l < len) {
    int i = b >> 5;
    int row = (pfx[c] + l) * 16 + i;
    float rs = 0.f, rq = 0.f;
    #pragma unroll
    for (int s = 0; s < 16; ++s) {
      rs += rs16[(size_t)s * 16384 + row];
      rq += rq16[(size_t)s * 16384 + row];
    }
    sv = rs / (sqrtf(rq) + EPSF);
  }
  #pragma unroll
  for (int off = 32; off > 0; off >>= 1) sv += __shfl_down(sv, off, 64);
  if (l == 0) out[b] = sv / (float)len;
}

extern "C" void kernel_launch(void* const* d_in, const int* in_sizes, int n_in,
                              void* d_out, int out_size, void* d_ws, size_t ws_size,
                              hipStream_t stream) {
  const float* img  = (const float*)d_in[0];   // (16,36,1024)
  const float* cap  = (const float*)d_in[1];   // (32,32,1024)
  const float* W    = (const float*)d_in[2];   // (1024,1024)
  const float* simw = (const float*)d_in[3];   // (1,1024)
  const float* tsw  = (const float*)d_in[4];   // (1,1)
  const float* tlw  = (const float*)d_in[5];   // (1,1)
  const int*   lens = (const int*)d_in[6];     // (32,)
  float* out = (float*)d_out;

  char* wsB = (char*)d_ws;
  if (ws_size < 51122176) return;   // needs ~48.8 MB scratch
  float* Dlw   = (float*)(wsB + 0);            // 4 MB (dead after k_diag_part -> reused)
  f16*   DlwH  = (f16*)  (wsB + 4194304);      // 2 MB
  float* diag  = (float*)(wsB + 6291456);      // 4 KB
  f16*   capH  = (f16*)  (wsB + 6295552);      // 2 MB
  f16*   imgdH = (f16*)  (wsB + 8392704);      // 1.5 MB (768 rows: 48/img, zero-padded)
  float* qk    = (float*)(wsB + 9965568);      // 3 MB  (1024 x 768)
  float* pw    = (float*)(wsB + 13111296);     // 2.25 MB (16 x 1024 x 36)
  f16*   slc   = (f16*)  (wsB + 15470592);     // 32 MB (compact rows x 1024)
  float* rs16  = (float*)(wsB + 49025024);     // 1 MB
  float* rq16  = (float*)(wsB + 50073600);     // 1 MB
  float* dpart = qk;                            // 64 KB, dead before k_qk writes qk
  f16*   imgH  = (f16*)Dlw;                     // 1.18 MB at +0 (Dlw dead after k_diag_part)
  int*   mp    = (int*)(wsB + 2097152);         // in dead Dlw region, past imgH
  int*   pfx   = (int*)(wsB + 2097152 + 256);   // 33 ints

  k_dlw<<<1024, 256, 0, stream>>>(W, simw, tlw, Dlw, DlwH);
  k_diag_part<<<dim3(4, 16), 256, 0, stream>>>(Dlw, dpart);
  k_diag2p<<<5, 256, 0, stream>>>(dpart, lens, diag, pfx, mp);  // Dlw region now dead
  k_prep<<<2368, 256, 0, stream>>>(cap, img, diag, capH, imgH, imgdH);
  k_qk<<<dim3(16, 16), 256, 0, stream>>>(capH, imgdH, qk);
  k_attnsm<<<512, 256, 0, stream>>>(qk, lens, tsw, pw);
  k_ctx<<<dim3(32, 16), 256, 0, stream>>>(pw, imgH, cap, lens, pfx, slc);
  k_gemm<<<dim3(128, 8), 256, 0, stream>>>(slc, DlwH, mp, rs16, rq16);
  k_final<<<512, 64, 0, stream>>>(rs16, rq16, lens, pfx, out);
}

// Round 11
// 106.809 us; speedup vs baseline: 1.0771x; 1.0771x over previous
//
#include <hip/hip_runtime.h>
#include <hip/hip_bf16.h>

#define I_N 16
#define C_N 32
#define L_N 32
#define R_N 36
#define D_N 1024
#define EPSF 1e-8f

typedef _Float16 f16;
typedef __attribute__((ext_vector_type(8))) _Float16 half8;
typedef __attribute__((ext_vector_type(4))) float floatx4;

// async global->LDS, 16B per lane; LDS dest = wave-uniform base + lane*16
__device__ __forceinline__ void gl16(const f16* g, f16* l) {
  __builtin_amdgcn_global_load_lds(
      (const __attribute__((address_space(1))) void*)g,
      (__attribute__((address_space(3))) void*)l, 16, 0, 0);
}

// ---------------- block-wide sum over 256 threads ----------------
__device__ __forceinline__ float blk_sum_256(float v, float* red) {
  #pragma unroll
  for (int off = 32; off > 0; off >>= 1) v += __shfl_down(v, off, 64);
  int wid = threadIdx.x >> 6;
  if ((threadIdx.x & 63) == 0) red[wid] = v;
  __syncthreads();
  float s = red[0] + red[1] + red[2] + red[3];
  __syncthreads();
  return s;
}

// ---------------- K1: Dim_learned_weights rows + f16 copy ----------------
// idx = floor(linspace(0,D,D)) clipped == identity -> weights = sigmoid(W)
__global__ __launch_bounds__(256) void k_dlw(const float* __restrict__ W,
    const float* __restrict__ simw, const float* __restrict__ tlw,
    float* __restrict__ Dlw, f16* __restrict__ DlwH) {
  int row = blockIdx.x, tid = threadIdx.x;
  __shared__ float red[4];
  const float* Wr = W + (size_t)row * D_N;
  float w[4]; float p = 0.f;
  #pragma unroll
  for (int k = 0; k < 4; ++k) {
    int j = tid + k * 256;
    float x = Wr[j];
    w[k] = 1.f / (1.f + expf(-x));
    p += w[k];
  }
  float S = blk_sum_256(p, red);
  float mean = S * (1.f / 1024.f);
  p = 0.f;
  #pragma unroll
  for (int k = 0; k < 4; ++k) { float d = w[k] - mean; p += d * d; }
  float S2 = blk_sum_256(p, red);
  float stdv = sqrtf(S2 * (1.f / 1023.f));   // ddof=1
  float thres = mean + simw[row] * stdv;
  float eT = expf(tlw[0]);
  float mw[4]; p = 0.f;
  #pragma unroll
  for (int k = 0; k < 4; ++k) {
    float val = eT * (w[k] - thres);
    float mp = tanhf(expf(val));
    mw[k] = mp * w[k];
    p += mw[k] * mw[k];
  }
  float S3 = blk_sum_256(p, red);
  float inv = 1.f / (sqrtf(S3) + EPSF);
  #pragma unroll
  for (int k = 0; k < 4; ++k) {
    int j = tid + k * 256;
    float v = mw[k] * inv;
    Dlw[(size_t)row * D_N + j] = v;
    DlwH[(size_t)row * D_N + j] = (f16)v;
  }
}

// ---------------- K2a: partial column sums of Dlw (64-row strips) ----------------
__global__ __launch_bounds__(256) void k_diag_part(const float* __restrict__ Dlw,
                                                   float* __restrict__ dpart) {
  int col = blockIdx.x * 256 + threadIdx.x;
  int p = blockIdx.y;                 // 0..15
  float s = 0.f;
  #pragma unroll 8
  for (int r = p * 64; r < p * 64 + 64; ++r) s += Dlw[(size_t)r * D_N + col];
  dpart[(size_t)p * D_N + col] = s;
}

// ---------------- K2b: fold partials -> diag, + prefix scan of cap_lens ----------------
// blocks 0..3: diag columns; block 4: pfx[c], mp = 16*sum(lens)
__global__ __launch_bounds__(256) void k_diag2p(const float* __restrict__ dpart,
    const int* __restrict__ lens, float* __restrict__ diag,
    int* __restrict__ pfx, int* __restrict__ mp) {
  if (blockIdx.x < 4) {
    int col = blockIdx.x * 256 + threadIdx.x;
    float s = 0.f;
    #pragma unroll
    for (int p = 0; p < 16; ++p) s += dpart[(size_t)p * D_N + col];
    diag[col] = s;
  } else if (threadIdx.x < 64) {
    int l = threadIdx.x;
    int v = (l < 32) ? lens[l] : 0;
    int s = v;
    #pragma unroll
    for (int off = 1; off < 32; off <<= 1) {
      int t = __shfl_up(s, off, 64);
      if (l >= off) s += t;
    }
    if (l < 32) pfx[l] = s - v;          // exclusive prefix
    if (l == 31) { pfx[32] = s; mp[0] = s * 16; }
  }
}

// ---------------- fused prep: cap->f16 | img->f16 | img*diag->f16 (padded 48) ----------------
__global__ __launch_bounds__(256) void k_prep(const float* __restrict__ cap,
    const float* __restrict__ img, const float* __restrict__ diag,
    f16* __restrict__ capH, f16* __restrict__ imgH, f16* __restrict__ imgdH) {
  int bid = blockIdx.x;
  if (bid < 1024) {
    size_t base = (size_t)bid * D_N;
    #pragma unroll
    for (int k = 0; k < 4; ++k) {
      int j = threadIdx.x + k * 256;
      capH[base + j] = (f16)cap[base + j];
    }
  } else if (bid < 1600) {
    size_t base = (size_t)(bid - 1024) * D_N;
    #pragma unroll
    for (int k = 0; k < 4; ++k) {
      int j = threadIdx.x + k * 256;
      imgH[base + j] = (f16)img[base + j];
    }
  } else {
    int row = bid - 1600;            // 0..767 = i*48 + r
    int i = row / 48, r = row % 48;
    size_t dst = (size_t)row * D_N;
    if (r < R_N) {
      size_t src = ((size_t)i * R_N + r) * D_N;
      #pragma unroll
      for (int k = 0; k < 4; ++k) {
        int j = threadIdx.x + k * 256;
        imgdH[dst + j] = (f16)(img[src + j] * diag[j]);
      }
    } else {
      #pragma unroll
      for (int k = 0; k < 4; ++k) {
        int j = threadIdx.x + k * 256;
        imgdH[dst + j] = (f16)0.f;
      }
    }
  }
}

// ---------------- K3: qk[m=(c,l)][i*48+n] = cap . (img*diag)  (MFMA f16) ----------------
// XOR-involution swizzle on BOTH ds_write and ds_read offsets (row bits 1..5 kept).
__global__ __launch_bounds__(256) void k_qk(const f16* __restrict__ A,
    const f16* __restrict__ B, float* __restrict__ qk) {
  int mt = blockIdx.x;             // 0..15
  int i  = blockIdx.y;             // 0..15
  int tid = threadIdx.x;
  int w = tid >> 6, lane = tid & 63;
  int l15 = lane & 15, h = lane >> 4;
  __shared__ __align__(16) f16 Als[64 * 32];
  __shared__ __align__(16) f16 Bls[48 * 32];
  floatx4 acc[3];
  #pragma unroll
  for (int nf = 0; nf < 3; ++nf) acc[nf] = (floatx4)0.f;
  int arow = tid >> 2;             // 0..63
  int u = tid & 3;                 // 16B unit within row
  int vf = (u | ((arow & 1) << 2)) ^ ((arow >> 1) & 7);
  int wofs = (((arow & 62) | (vf >> 2)) * 32) + (vf & 3) * 8;
  const f16* Ag = A + (size_t)(mt * 64 + arow) * D_N + u * 8;
  const f16* Bg = B + (size_t)(i * 48 + arow) * D_N + u * 8;
  int v2 = (h | ((l15 & 1) << 2)) ^ ((l15 >> 1) & 7);
  int rbit = (v2 >> 2) & 1;
  int pun = (v2 & 3) * 8;
  int aoff = (w * 16 + (l15 & 14) + rbit) * 32 + pun;
  int boff[3];
  #pragma unroll
  for (int nf = 0; nf < 3; ++nf) boff[nf] = (nf * 16 + (l15 & 14) + rbit) * 32 + pun;
  for (int kk = 0; kk < D_N; kk += 32) {
    *(float4*)(&Als[wofs]) = *(const float4*)(Ag + kk);
    if (tid < 192) *(float4*)(&Bls[wofs]) = *(const float4*)(Bg + kk);
    __syncthreads();
    half8 a = *(const half8*)(&Als[aoff]);
    #pragma unroll
    for (int nf = 0; nf < 3; ++nf) {
      half8 b = *(const half8*)(&Bls[boff[nf]]);
      acc[nf] = __builtin_amdgcn_mfma_f32_16x16x32_f16(a, b, acc[nf], 0, 0, 0);
    }
    __syncthreads();
  }
  #pragma unroll
  for (int nf = 0; nf < 3; ++nf)
    #pragma unroll
    for (int j = 0; j < 4; ++j) {
      int m = mt * 64 + w * 16 + h * 4 + j;
      int n = nf * 16 + l15;
      qk[(size_t)m * 768 + i * 48 + n] = acc[nf][j];
    }
}

// ---------------- K4: tanh/leaky/mask -> l2norm over words -> softmax over regions ----------------
__global__ __launch_bounds__(256) void k_attnsm(const float* __restrict__ qk,
    const int* __restrict__ lens, const float* __restrict__ tsw,
    float* __restrict__ pw) {
  int c = blockIdx.x >> 4, i = blockIdx.x & 15;
  int tid = threadIdx.x;
  int len = lens[c];
  float smooth = expf(tsw[0]);
  __shared__ float att[L_N][R_N];
  __shared__ float cn[R_N];
  for (int e = tid; e < L_N * R_N; e += 256) {
    int l = e / R_N, r = e % R_N;
    float x = qk[(size_t)(c * 32 + l) * 768 + i * 48 + r];
    float t = tanhf(x);
    float v = (t >= 0.f) ? t : 0.1f * t;   // LeakyReLU(0.1)
    if (l >= len) v = 0.f;                 // word mask
    att[l][r] = v;
  }
  __syncthreads();
  if (tid < R_N) {                          // l2norm over word dim
    float s = 0.f;
    #pragma unroll
    for (int l = 0; l < L_N; ++l) s += att[l][tid] * att[l][tid];
    cn[tid] = sqrtf(s) + EPSF;
  }
  __syncthreads();
  if (tid < L_N) {                          // softmax over regions
    float z[R_N];
    float mx = -3.4e38f;
    #pragma unroll
    for (int r = 0; r < R_N; ++r) { z[r] = att[tid][r] / cn[r] * smooth; mx = fmaxf(mx, z[r]); }
    float se = 0.f;
    #pragma unroll
    for (int r = 0; r < R_N; ++r) { float e = expf(z[r] - mx); z[r] = e; se += e; }
    float inv = 1.f / se;
    #pragma unroll
    for (int r = 0; r < R_N; ++r) att[tid][r] = z[r] * inv;
  }
  __syncthreads();
  for (int e = tid; e < L_N * R_N; e += 256) {
    int l = e / R_N, r = e % R_N;
    pw[((size_t)i * 1024 + c * 32 + l) * R_N + r] = att[l][r];
  }
}

// ---------------- K5: ctx = attn @ img[i]; l2norm; * cap -> COMPACT sim_loc (f16) ----------------
// One block per (caption, image): stage img[i] ONCE (72 KB), two 16-row sub-passes.
__global__ __launch_bounds__(256) void k_ctx(const float* __restrict__ pw,
    const f16* __restrict__ imgH, const float* __restrict__ cap,
    const int* __restrict__ lens, const int* __restrict__ pfx,
    f16* __restrict__ slc) {
  int c  = blockIdx.x;             // 0..31 caption
  int i  = blockIdx.y;             // 0..15 image
  int tid = threadIdx.x;
  int w = tid >> 6;                // wave id
  int cg = tid & 63;
  int len = lens[c];
  int pf = pfx[c];
  __shared__ float pA[32][R_N];
  __shared__ __align__(16) f16 rows[R_N][1024];   // 72 KB
  for (int e = tid; e < 32 * R_N; e += 256) {
    int rr = e / R_N, r = e % R_N;
    pA[rr][r] = pw[((size_t)i * 1024 + c * 32 + rr) * R_N + r];
  }
  const f16* base = imgH + (size_t)i * R_N * D_N;
  #pragma unroll
  for (int t = 0; t < 9; ++t) {
    int rr = w * 9 + t;
    const f16* src = base + (size_t)rr * D_N + cg * 8;
    gl16(src,       &rows[rr][0]);
    gl16(src + 512, &rows[rr][512]);
  }
  __syncthreads();                 // drains vmcnt + lgkm once
  int d0 = cg * 8, d1 = 512 + cg * 8;
  #pragma unroll
  for (int sub = 0; sub < 2; ++sub) {
    float acc[4][16];
    #pragma unroll
    for (int j = 0; j < 4; ++j)
      #pragma unroll
      for (int q = 0; q < 16; ++q) acc[j][q] = 0.f;
    for (int k = 0; k < R_N; ++k) {
      half8 h0 = *(const half8*)(&rows[k][d0]);
      half8 h1 = *(const half8*)(&rows[k][d1]);
      float bv[16];
      #pragma unroll
      for (int q = 0; q < 8; ++q) { bv[q] = (float)h0[q]; bv[8 + q] = (float)h1[q]; }
      #pragma unroll
      for (int j = 0; j < 4; ++j) {
        float a = pA[sub * 16 + w * 4 + j][k];
        #pragma unroll
        for (int q = 0; q < 16; ++q) acc[j][q] += a * bv[q];
      }
    }
    #pragma unroll
    for (int j = 0; j < 4; ++j) {
      int l = sub * 16 + w * 4 + j;      // word index 0..31
      float ss = 0.f;
      #pragma unroll
      for (int q = 0; q < 16; ++q) ss += acc[j][q] * acc[j][q];
      #pragma unroll
      for (int off = 1; off < 64; off <<= 1) ss += __shfl_xor(ss, off, 64);
      if (l < len) {
        float inv = 1.f / (sqrtf(ss) + EPSF);
        const float* capr = cap + ((size_t)c * L_N + l) * D_N;
        float4 c0 = *(const float4*)(capr + d0);
        float4 c1 = *(const float4*)(capr + d0 + 4);
        float4 c2 = *(const float4*)(capr + d1);
        float4 c3 = *(const float4*)(capr + d1 + 4);
        float cv[16] = {c0.x,c0.y,c0.z,c0.w, c1.x,c1.y,c1.z,c1.w,
                        c2.x,c2.y,c2.z,c2.w, c3.x,c3.y,c3.z,c3.w};
        union { f16 h[16]; float4 f4[2]; } u;
        #pragma unroll
        for (int q = 0; q < 16; ++q) u.h[q] = (f16)(acc[j][q] * inv * cv[q]);
        f16* dst = slc + ((size_t)((pf + l) * 16 + i)) * D_N;
        *(float4*)(dst + d0) = u.f4[0];
        *(float4*)(dst + d1) = u.f4[1];
      }
    }
  }
}

// ---------------- K6: big GEMM (compacted M) f16 MFMA, fused rowsum/rowsumsq ----------------
// 128x128 tile, BK=32, 4 waves 2x2. TRIPLE-buffered LDS, depth-2 prefetch via
// global_load_lds + inverse-swizzled global source + swizzled ds_read offsets.
// EXACT R9 sync structure (proven; R10's 2-buffer depth-1 stalled on vmcnt —
// depth-2 is needed to hide ~500cy load latency across two COMPUTE phases).
__global__ __launch_bounds__(256) void k_gemm(const f16* __restrict__ A,
    const f16* __restrict__ B, const int* __restrict__ mp,
    float* __restrict__ rs16, float* __restrict__ rq16) {
  int bx = blockIdx.x, by = blockIdx.y;
  int Mp = mp[0];
  int m0 = bx * 128, n0 = by * 128;
  if (m0 >= Mp) return;            // uniform per block; compacted tail
  int tid = threadIdx.x;
  int w = tid >> 6, lane = tid & 63;
  int l15 = lane & 15, h = lane >> 4;
  int wm = w >> 1, wn = w & 1;
  __shared__ __align__(16) f16 AB[3][2][128 * 32];   // 48 KB
  floatx4 acc[4][4];
  #pragma unroll
  for (int mf = 0; mf < 4; ++mf)
    #pragma unroll
    for (int nf = 0; nf < 4; ++nf) acc[mf][nf] = (floatx4)0.f;

  // ---- staging: lane's linear LDS slot (r_p,u_p) must receive logical (r_l,u_l)
  int r_p = lane >> 2, u_p = lane & 3;
  int sw = (r_p >> 1) & 7;
  int val = (u_p | ((r_p & 1) << 2)) ^ sw;
  int r_l = (r_p & 14) | (val >> 2);
  int u_l = val & 3;
  const f16* As0 = A + (size_t)(m0 + w * 32 +  0 + r_l) * D_N + u_l * 8;
  const f16* As1 = A + (size_t)(m0 + w * 32 + 16 + r_l) * D_N + u_l * 8;
  const f16* Bs0 = B + (size_t)(n0 + w * 32 +  0 + r_l) * D_N + u_l * 8;
  const f16* Bs1 = B + (size_t)(n0 + w * 32 + 16 + r_l) * D_N + u_l * 8;

  // ---- fragment reads: physical (swizzled) offsets, loop-invariant
  int v2 = (h | ((l15 & 1) << 2)) ^ ((l15 >> 1) & 7);
  int rbit = (v2 >> 2) & 1;
  int pun = (v2 & 3) * 8;
  int aoff[4], boff[4];
  #pragma unroll
  for (int f = 0; f < 4; ++f) {
    aoff[f] = (wm * 64 + f * 16 + (l15 & 14) + rbit) * 32 + pun;
    boff[f] = (wn * 64 + f * 16 + (l15 & 14) + rbit) * 32 + pun;
  }

  #define STAGE(kt, b) { \
    int kof = (kt) * 32; \
    gl16(As0 + kof, &AB[b][0][(w * 32 +  0) * 32]); \
    gl16(As1 + kof, &AB[b][0][(w * 32 + 16) * 32]); \
    gl16(Bs0 + kof, &AB[b][1][(w * 32 +  0) * 32]); \
    gl16(Bs1 + kof, &AB[b][1][(w * 32 + 16) * 32]); }

  #define COMPUTE(b) { \
    half8 af[4], bf[4]; \
    _Pragma("unroll") for (int f = 0; f < 4; ++f) af[f] = *(const half8*)(&AB[b][0][aoff[f]]); \
    _Pragma("unroll") for (int f = 0; f < 4; ++f) bf[f] = *(const half8*)(&AB[b][1][boff[f]]); \
    _Pragma("unroll") for (int mf = 0; mf < 4; ++mf) \
      _Pragma("unroll") for (int nf = 0; nf < 4; ++nf) \
        acc[mf][nf] = __builtin_amdgcn_mfma_f32_16x16x32_f16(af[mf], bf[nf], acc[mf][nf], 0, 0, 0); }

  STAGE(0, 0);
  STAGE(1, 1);
  int cur = 0, n2 = 2;
  for (int kk = 0; kk < 30; ++kk) {
    STAGE(kk + 2, n2);
    asm volatile("s_waitcnt vmcnt(8)" ::: "memory");  // tile kk's 4 loads done
    __builtin_amdgcn_s_barrier();
    __builtin_amdgcn_sched_barrier(0);
    COMPUTE(cur);
    __builtin_amdgcn_s_barrier();                     // all reads of cur done
    cur = (cur == 2) ? 0 : cur + 1;
    n2  = (n2  == 2) ? 0 : n2  + 1;
  }
  asm volatile("s_waitcnt vmcnt(4)" ::: "memory");
  __builtin_amdgcn_s_barrier();
  __builtin_amdgcn_sched_barrier(0);
  COMPUTE(cur);
  __builtin_amdgcn_s_barrier();
  cur = (cur == 2) ? 0 : cur + 1;
  asm volatile("s_waitcnt vmcnt(0)" ::: "memory");
  __builtin_amdgcn_s_barrier();
  __builtin_amdgcn_sched_barrier(0);
  COMPUTE(cur);
  #undef STAGE
  #undef COMPUTE

  int slot = by * 2 + wn;          // 0..15, deterministic partials (no atomics)
  #pragma unroll
  for (int mf = 0; mf < 4; ++mf)
    #pragma unroll
    for (int j = 0; j < 4; ++j) {
      float s = 0.f, q = 0.f;
      #pragma unroll
      for (int nf = 0; nf < 4; ++nf) { float v = acc[mf][nf][j]; s += v; q += v * v; }
      #pragma unroll
      for (int off = 1; off < 16; off <<= 1) { s += __shfl_xor(s, off, 64); q += __shfl_xor(q, off, 64); }
      if (l15 == 0) {
        int m = m0 + wm * 64 + mf * 16 + h * 4 + j;
        rs16[(size_t)slot * 16384 + m] = s;
        rq16[(size_t)slot * 16384 + m] = q;
      }
    }
}

// ---------------- K7: sim[i][c] — one block per (i,c), lane per word (compact rows) ----------------
__global__ __launch_bounds__(64) void k_final(const float* __restrict__ rs16,
    const float* __restrict__ rq16, const int* __restrict__ lens,
    const int* __restrict__ pfx, float* __restrict__ out) {
  int b = blockIdx.x;              // 0..511 = i*32 + c
  int c = b & 31;
  int l = threadIdx.x;             // 0..63, words are 0..31
  int len = lens[c];
  float sv = 0.f;
  if (l < len) {
    int i = b >> 5;
    int row = (pfx[c] + l) * 16 + i;
    float rs = 0.f, rq = 0.f;
    #pragma unroll
    for (int s = 0; s < 16; ++s) {
      rs += rs16[(size_t)s * 16384 + row];
      rq += rq16[(size_t)s * 16384 + row];
    }
    sv = rs / (sqrtf(rq) + EPSF);
  }
  #pragma unroll
  for (int off = 32; off > 0; off >>= 1) sv += __shfl_down(sv, off, 64);
  if (l == 0) out[b] = sv / (float)len;
}

extern "C" void kernel_launch(void* const* d_in, const int* in_sizes, int n_in,
                              void* d_out, int out_size, void* d_ws, size_t ws_size,
                              hipStream_t stream) {
  const float* img  = (const float*)d_in[0];   // (16,36,1024)
  const float* cap  = (const float*)d_in[1];   // (32,32,1024)
  const float* W    = (const float*)d_in[2];   // (1024,1024)
  const float* simw = (const float*)d_in[3];   // (1,1024)
  const float* tsw  = (const float*)d_in[4];   // (1,1)
  const float* tlw  = (const float*)d_in[5];   // (1,1)
  const int*   lens = (const int*)d_in[6];     // (32,)
  float* out = (float*)d_out;

  char* wsB = (char*)d_ws;
  if (ws_size < 51122176) return;   // needs ~48.8 MB scratch
  float* Dlw   = (float*)(wsB + 0);            // 4 MB (dead after k_diag_part -> reused)
  f16*   DlwH  = (f16*)  (wsB + 4194304);      // 2 MB
  float* diag  = (float*)(wsB + 6291456);      // 4 KB
  f16*   capH  = (f16*)  (wsB + 6295552);      // 2 MB
  f16*   imgdH = (f16*)  (wsB + 8392704);      // 1.5 MB (768 rows: 48/img, zero-padded)
  float* qk    = (float*)(wsB + 9965568);      // 3 MB  (1024 x 768)
  float* pw    = (float*)(wsB + 13111296);     // 2.25 MB (16 x 1024 x 36)
  f16*   slc   = (f16*)  (wsB + 15470592);     // 32 MB (compact rows x 1024)
  float* rs16  = (float*)(wsB + 49025024);     // 1 MB
  float* rq16  = (float*)(wsB + 50073600);     // 1 MB
  float* dpart = qk;                            // 64 KB, dead before k_qk writes qk
  f16*   imgH  = (f16*)Dlw;                     // 1.18 MB at +0 (Dlw dead after k_diag_part)
  int*   mp    = (int*)(wsB + 2097152);         // in dead Dlw region, past imgH
  int*   pfx   = (int*)(wsB + 2097152 + 256);   // 33 ints

  k_dlw<<<1024, 256, 0, stream>>>(W, simw, tlw, Dlw, DlwH);
  k_diag_part<<<dim3(4, 16), 256, 0, stream>>>(Dlw, dpart);
  k_diag2p<<<5, 256, 0, stream>>>(dpart, lens, diag, pfx, mp);  // Dlw region now dead
  k_prep<<<2368, 256, 0, stream>>>(cap, img, diag, capH, imgH, imgdH);
  k_qk<<<dim3(16, 16), 256, 0, stream>>>(capH, imgdH, qk);
  k_attnsm<<<512, 256, 0, stream>>>(qk, lens, tsw, pw);
  k_ctx<<<dim3(32, 16), 256, 0, stream>>>(pw, imgH, cap, lens, pfx, slc);
  k_gemm<<<dim3(128, 8), 256, 0, stream>>>(slc, DlwH, mp, rs16, rq16);
  k_final<<<512, 64, 0, stream>>>(rs16, rq16, lens, pfx, out);
}

// Round 12
// 103.464 us; speedup vs baseline: 1.1119x; 1.0323x over previous
//
#include <hip/hip_runtime.h>
#include <hip/hip_bf16.h>

#define I_N 16
#define C_N 32
#define L_N 32
#define R_N 36
#define D_N 1024
#define EPSF 1e-8f

typedef _Float16 f16;
typedef __attribute__((ext_vector_type(8))) _Float16 half8;
typedef __attribute__((ext_vector_type(4))) float floatx4;

// async global->LDS, 16B per lane; LDS dest = wave-uniform base + lane*16
__device__ __forceinline__ void gl16(const f16* g, f16* l) {
  __builtin_amdgcn_global_load_lds(
      (const __attribute__((address_space(1))) void*)g,
      (__attribute__((address_space(3))) void*)l, 16, 0, 0);
}

// fast stable tanh via v_exp: tanh(x) = sign(x) * (1-e^{-2|x|})/(1+e^{-2|x|})
__device__ __forceinline__ float fast_tanh(float x) {
  float q = __expf(-2.f * fabsf(x));
  float t = (1.f - q) / (1.f + q);
  return (x >= 0.f) ? t : -t;
}

// ---------------- block-wide sum over 256 threads ----------------
__device__ __forceinline__ float blk_sum_256(float v, float* red) {
  #pragma unroll
  for (int off = 32; off > 0; off >>= 1) v += __shfl_down(v, off, 64);
  int wid = threadIdx.x >> 6;
  if ((threadIdx.x & 63) == 0) red[wid] = v;
  __syncthreads();
  float s = red[0] + red[1] + red[2] + red[3];
  __syncthreads();
  return s;
}

// ---------------- K1: Dim_learned_weights rows + f16 copy ----------------
// idx = floor(linspace(0,D,D)) clipped == identity -> weights = sigmoid(W)
__global__ __launch_bounds__(256) void k_dlw(const float* __restrict__ W,
    const float* __restrict__ simw, const float* __restrict__ tlw,
    float* __restrict__ Dlw, f16* __restrict__ DlwH) {
  int row = blockIdx.x, tid = threadIdx.x;
  __shared__ float red[4];
  const float* Wr = W + (size_t)row * D_N;
  float w[4]; float p = 0.f;
  #pragma unroll
  for (int k = 0; k < 4; ++k) {
    int j = tid + k * 256;
    float x = Wr[j];
    w[k] = 1.f / (1.f + __expf(-x));
    p += w[k];
  }
  float S = blk_sum_256(p, red);
  float mean = S * (1.f / 1024.f);
  p = 0.f;
  #pragma unroll
  for (int k = 0; k < 4; ++k) { float d = w[k] - mean; p += d * d; }
  float S2 = blk_sum_256(p, red);
  float stdv = sqrtf(S2 * (1.f / 1023.f));   // ddof=1
  float thres = mean + simw[row] * stdv;
  float eT = __expf(tlw[0]);
  float mw[4]; p = 0.f;
  #pragma unroll
  for (int k = 0; k < 4; ++k) {
    float val = eT * (w[k] - thres);
    float y = __expf(val);                 // >= 0; inf ok (tanh->1)
    float q = __expf(-2.f * y);
    float mp = (1.f - q) / (1.f + q);      // tanh(y), y>=0
    mw[k] = mp * w[k];
    p += mw[k] * mw[k];
  }
  float S3 = blk_sum_256(p, red);
  float inv = 1.f / (sqrtf(S3) + EPSF);
  #pragma unroll
  for (int k = 0; k < 4; ++k) {
    int j = tid + k * 256;
    float v = mw[k] * inv;
    Dlw[(size_t)row * D_N + j] = v;
    DlwH[(size_t)row * D_N + j] = (f16)v;
  }
}

// ---------------- K2a: partial column sums of Dlw (64-row strips) ----------------
__global__ __launch_bounds__(256) void k_diag_part(const float* __restrict__ Dlw,
                                                   float* __restrict__ dpart) {
  int col = blockIdx.x * 256 + threadIdx.x;
  int p = blockIdx.y;                 // 0..15
  float s = 0.f;
  #pragma unroll 8
  for (int r = p * 64; r < p * 64 + 64; ++r) s += Dlw[(size_t)r * D_N + col];
  dpart[(size_t)p * D_N + col] = s;
}

// ---------------- K2b: fold partials -> diag, + prefix scan of cap_lens ----------------
// blocks 0..3: diag columns; block 4: pfx[c], mp = 16*sum(lens)
__global__ __launch_bounds__(256) void k_diag2p(const float* __restrict__ dpart,
    const int* __restrict__ lens, float* __restrict__ diag,
    int* __restrict__ pfx, int* __restrict__ mp) {
  if (blockIdx.x < 4) {
    int col = blockIdx.x * 256 + threadIdx.x;
    float s = 0.f;
    #pragma unroll
    for (int p = 0; p < 16; ++p) s += dpart[(size_t)p * D_N + col];
    diag[col] = s;
  } else if (threadIdx.x < 64) {
    int l = threadIdx.x;
    int v = (l < 32) ? lens[l] : 0;
    int s = v;
    #pragma unroll
    for (int off = 1; off < 32; off <<= 1) {
      int t = __shfl_up(s, off, 64);
      if (l >= off) s += t;
    }
    if (l < 32) pfx[l] = s - v;          // exclusive prefix
    if (l == 31) { pfx[32] = s; mp[0] = s * 16; }
  }
}

// ---------------- fused prep: cap->f16 | img->f16 | img*diag->f16 (padded 48) ----------------
__global__ __launch_bounds__(256) void k_prep(const float* __restrict__ cap,
    const float* __restrict__ img, const float* __restrict__ diag,
    f16* __restrict__ capH, f16* __restrict__ imgH, f16* __restrict__ imgdH) {
  int bid = blockIdx.x;
  if (bid < 1024) {
    size_t base = (size_t)bid * D_N;
    #pragma unroll
    for (int k = 0; k < 4; ++k) {
      int j = threadIdx.x + k * 256;
      capH[base + j] = (f16)cap[base + j];
    }
  } else if (bid < 1600) {
    size_t base = (size_t)(bid - 1024) * D_N;
    #pragma unroll
    for (int k = 0; k < 4; ++k) {
      int j = threadIdx.x + k * 256;
      imgH[base + j] = (f16)img[base + j];
    }
  } else {
    int row = bid - 1600;            // 0..767 = i*48 + r
    int i = row / 48, r = row % 48;
    size_t dst = (size_t)row * D_N;
    if (r < R_N) {
      size_t src = ((size_t)i * R_N + r) * D_N;
      #pragma unroll
      for (int k = 0; k < 4; ++k) {
        int j = threadIdx.x + k * 256;
        imgdH[dst + j] = (f16)(img[src + j] * diag[j]);
      }
    } else {
      #pragma unroll
      for (int k = 0; k < 4; ++k) {
        int j = threadIdx.x + k * 256;
        imgdH[dst + j] = (f16)0.f;
      }
    }
  }
}

// ---------------- K3: qk MFMA + FUSED attn epilogue -> pw ----------------
// Block (mt,i) owns 64 rows = captions 2mt,2mt+1 x image i, all 48 cols.
// After MFMA: tanh/leaky/mask -> per-caption word-l2norm -> region-softmax -> pw.
__global__ __launch_bounds__(256) void k_qk(const f16* __restrict__ A,
    const f16* __restrict__ B, const int* __restrict__ lens,
    const float* __restrict__ tsw, float* __restrict__ pw) {
  int mt = blockIdx.x;             // 0..15
  int i  = blockIdx.y;             // 0..15
  int tid = threadIdx.x;
  int w = tid >> 6, lane = tid & 63;
  int l15 = lane & 15, h = lane >> 4;
  __shared__ __align__(16) f16 Als[64 * 32];
  __shared__ __align__(16) f16 Bls[48 * 32];
  __shared__ float att[64][49];    // +1 pad breaks column-sum conflicts
  __shared__ float cn[2][R_N];
  floatx4 acc[3];
  #pragma unroll
  for (int nf = 0; nf < 3; ++nf) acc[nf] = (floatx4)0.f;
  int arow = tid >> 2;             // 0..63
  int u = tid & 3;                 // 16B unit within row
  int vf = (u | ((arow & 1) << 2)) ^ ((arow >> 1) & 7);
  int wofs = (((arow & 62) | (vf >> 2)) * 32) + (vf & 3) * 8;
  const f16* Ag = A + (size_t)(mt * 64 + arow) * D_N + u * 8;
  const f16* Bg = B + (size_t)(i * 48 + arow) * D_N + u * 8;
  int v2 = (h | ((l15 & 1) << 2)) ^ ((l15 >> 1) & 7);
  int rbit = (v2 >> 2) & 1;
  int pun = (v2 & 3) * 8;
  int aoff = (w * 16 + (l15 & 14) + rbit) * 32 + pun;
  int boff[3];
  #pragma unroll
  for (int nf = 0; nf < 3; ++nf) boff[nf] = (nf * 16 + (l15 & 14) + rbit) * 32 + pun;
  for (int kk = 0; kk < D_N; kk += 32) {
    *(float4*)(&Als[wofs]) = *(const float4*)(Ag + kk);
    if (tid < 192) *(float4*)(&Bls[wofs]) = *(const float4*)(Bg + kk);
    __syncthreads();
    half8 a = *(const half8*)(&Als[aoff]);
    #pragma unroll
    for (int nf = 0; nf < 3; ++nf) {
      half8 b = *(const half8*)(&Bls[boff[nf]]);
      acc[nf] = __builtin_amdgcn_mfma_f32_16x16x32_f16(a, b, acc[nf], 0, 0, 0);
    }
    __syncthreads();
  }
  // ---- fused epilogue (was k_attnsm) ----
  int len0 = lens[mt * 2], len1 = lens[mt * 2 + 1];
  #pragma unroll
  for (int nf = 0; nf < 3; ++nf)
    #pragma unroll
    for (int j = 0; j < 4; ++j) {
      int ml = w * 16 + h * 4 + j;           // 0..63
      int n = nf * 16 + l15;                 // 0..47
      float t = fast_tanh(acc[nf][j]);
      float v = (t >= 0.f) ? t : 0.1f * t;   // LeakyReLU(0.1)
      int len = (ml >= 32) ? len1 : len0;
      if ((ml & 31) >= len || n >= R_N) v = 0.f;   // word mask + col pad
      att[ml][n] = v;
    }
  __syncthreads();
  for (int e = tid; e < 2 * R_N; e += 256) {       // word-dim l2norm, per caption
    int cc = e / R_N, r = e % R_N;
    float s = 0.f;
    #pragma unroll
    for (int l = 0; l < 32; ++l) { float a = att[cc * 32 + l][r]; s += a * a; }
    cn[cc][r] = sqrtf(s) + EPSF;
  }
  __syncthreads();
  if (tid < 64) {                                  // softmax over regions, per row
    int cc = tid >> 5, l = tid & 31;
    float smooth = __expf(tsw[0]);
    float mx = -3.4e38f;
    #pragma unroll
    for (int r = 0; r < R_N; ++r) {
      float z = att[tid][r] / cn[cc][r] * smooth;
      att[tid][r] = z;
      mx = fmaxf(mx, z);
    }
    float se = 0.f;
    #pragma unroll
    for (int r = 0; r < R_N; ++r) {
      float e2 = __expf(att[tid][r] - mx);
      att[tid][r] = e2;
      se += e2;
    }
    float inv = 1.f / se;
    float* dst = pw + ((size_t)i * 1024 + (mt * 2 + cc) * 32 + l) * R_N;
    #pragma unroll
    for (int r = 0; r < R_N; ++r) dst[r] = att[tid][r] * inv;
  }
}

// ---------------- K5: ctx = attn @ img[i]; l2norm; * cap -> COMPACT sim_loc (f16) ----------------
// One block per (caption, image): stage img[i] ONCE (72 KB), two 16-row sub-passes.
__global__ __launch_bounds__(256) void k_ctx(const float* __restrict__ pw,
    const f16* __restrict__ imgH, const float* __restrict__ cap,
    const int* __restrict__ lens, const int* __restrict__ pfx,
    f16* __restrict__ slc) {
  int c  = blockIdx.x;             // 0..31 caption
  int i  = blockIdx.y;             // 0..15 image
  int tid = threadIdx.x;
  int w = tid >> 6;                // wave id
  int cg = tid & 63;
  int len = lens[c];
  int pf = pfx[c];
  __shared__ float pA[32][R_N];
  __shared__ __align__(16) f16 rows[R_N][1024];   // 72 KB
  for (int e = tid; e < 32 * R_N; e += 256) {
    int rr = e / R_N, r = e % R_N;
    pA[rr][r] = pw[((size_t)i * 1024 + c * 32 + rr) * R_N + r];
  }
  const f16* base = imgH + (size_t)i * R_N * D_N;
  #pragma unroll
  for (int t = 0; t < 9; ++t) {
    int rr = w * 9 + t;
    const f16* src = base + (size_t)rr * D_N + cg * 8;
    gl16(src,       &rows[rr][0]);
    gl16(src + 512, &rows[rr][512]);
  }
  __syncthreads();                 // drains vmcnt + lgkm once
  int d0 = cg * 8, d1 = 512 + cg * 8;
  #pragma unroll
  for (int sub = 0; sub < 2; ++sub) {
    float acc[4][16];
    #pragma unroll
    for (int j = 0; j < 4; ++j)
      #pragma unroll
      for (int q = 0; q < 16; ++q) acc[j][q] = 0.f;
    for (int k = 0; k < R_N; ++k) {
      half8 h0 = *(const half8*)(&rows[k][d0]);
      half8 h1 = *(const half8*)(&rows[k][d1]);
      float bv[16];
      #pragma unroll
      for (int q = 0; q < 8; ++q) { bv[q] = (float)h0[q]; bv[8 + q] = (float)h1[q]; }
      #pragma unroll
      for (int j = 0; j < 4; ++j) {
        float a = pA[sub * 16 + w * 4 + j][k];
        #pragma unroll
        for (int q = 0; q < 16; ++q) acc[j][q] += a * bv[q];
      }
    }
    #pragma unroll
    for (int j = 0; j < 4; ++j) {
      int l = sub * 16 + w * 4 + j;      // word index 0..31
      float ss = 0.f;
      #pragma unroll
      for (int q = 0; q < 16; ++q) ss += acc[j][q] * acc[j][q];
      #pragma unroll
      for (int off = 1; off < 64; off <<= 1) ss += __shfl_xor(ss, off, 64);
      if (l < len) {
        float inv = 1.f / (sqrtf(ss) + EPSF);
        const float* capr = cap + ((size_t)c * L_N + l) * D_N;
        float4 c0 = *(const float4*)(capr + d0);
        float4 c1 = *(const float4*)(capr + d0 + 4);
        float4 c2 = *(const float4*)(capr + d1);
        float4 c3 = *(const float4*)(capr + d1 + 4);
        float cv[16] = {c0.x,c0.y,c0.z,c0.w, c1.x,c1.y,c1.z,c1.w,
                        c2.x,c2.y,c2.z,c2.w, c3.x,c3.y,c3.z,c3.w};
        union { f16 h[16]; float4 f4[2]; } u;
        #pragma unroll
        for (int q = 0; q < 16; ++q) u.h[q] = (f16)(acc[j][q] * inv * cv[q]);
        f16* dst = slc + ((size_t)((pf + l) * 16 + i)) * D_N;
        *(float4*)(dst + d0) = u.f4[0];
        *(float4*)(dst + d1) = u.f4[1];
      }
    }
  }
}

// ---------------- K6: big GEMM (compacted M) f16 MFMA, fused rowsum/rowsumsq ----------------
// 128x128 tile, BK=32, 4 waves 2x2. TRIPLE-buffered LDS, depth-2 prefetch via
// global_load_lds + inverse-swizzled global source + swizzled ds_read offsets.
// EXACT R9/R11 sync structure (proven; depth-1 stalls on vmcnt — R10 lesson).
__global__ __launch_bounds__(256) void k_gemm(const f16* __restrict__ A,
    const f16* __restrict__ B, const int* __restrict__ mp,
    float* __restrict__ rs16, float* __restrict__ rq16) {
  int bx = blockIdx.x, by = blockIdx.y;
  int Mp = mp[0];
  int m0 = bx * 128, n0 = by * 128;
  if (m0 >= Mp) return;            // uniform per block; compacted tail
  int tid = threadIdx.x;
  int w = tid >> 6, lane = tid & 63;
  int l15 = lane & 15, h = lane >> 4;
  int wm = w >> 1, wn = w & 1;
  __shared__ __align__(16) f16 AB[3][2][128 * 32];   // 48 KB
  floatx4 acc[4][4];
  #pragma unroll
  for (int mf = 0; mf < 4; ++mf)
    #pragma unroll
    for (int nf = 0; nf < 4; ++nf) acc[mf][nf] = (floatx4)0.f;

  // ---- staging: lane's linear LDS slot (r_p,u_p) must receive logical (r_l,u_l)
  int r_p = lane >> 2, u_p = lane & 3;
  int sw = (r_p >> 1) & 7;
  int val = (u_p | ((r_p & 1) << 2)) ^ sw;
  int r_l = (r_p & 14) | (val >> 2);
  int u_l = val & 3;
  const f16* As0 = A + (size_t)(m0 + w * 32 +  0 + r_l) * D_N + u_l * 8;
  const f16* As1 = A + (size_t)(m0 + w * 32 + 16 + r_l) * D_N + u_l * 8;
  const f16* Bs0 = B + (size_t)(n0 + w * 32 +  0 + r_l) * D_N + u_l * 8;
  const f16* Bs1 = B + (size_t)(n0 + w * 32 + 16 + r_l) * D_N + u_l * 8;

  // ---- fragment reads: physical (swizzled) offsets, loop-invariant
  int v2 = (h | ((l15 & 1) << 2)) ^ ((l15 >> 1) & 7);
  int rbit = (v2 >> 2) & 1;
  int pun = (v2 & 3) * 8;
  int aoff[4], boff[4];
  #pragma unroll
  for (int f = 0; f < 4; ++f) {
    aoff[f] = (wm * 64 + f * 16 + (l15 & 14) + rbit) * 32 + pun;
    boff[f] = (wn * 64 + f * 16 + (l15 & 14) + rbit) * 32 + pun;
  }

  #define STAGE(kt, b) { \
    int kof = (kt) * 32; \
    gl16(As0 + kof, &AB[b][0][(w * 32 +  0) * 32]); \
    gl16(As1 + kof, &AB[b][0][(w * 32 + 16) * 32]); \
    gl16(Bs0 + kof, &AB[b][1][(w * 32 +  0) * 32]); \
    gl16(Bs1 + kof, &AB[b][1][(w * 32 + 16) * 32]); }

  #define COMPUTE(b) { \
    half8 af[4], bf[4]; \
    _Pragma("unroll") for (int f = 0; f < 4; ++f) af[f] = *(const half8*)(&AB[b][0][aoff[f]]); \
    _Pragma("unroll") for (int f = 0; f < 4; ++f) bf[f] = *(const half8*)(&AB[b][1][boff[f]]); \
    _Pragma("unroll") for (int mf = 0; mf < 4; ++mf) \
      _Pragma("unroll") for (int nf = 0; nf < 4; ++nf) \
        acc[mf][nf] = __builtin_amdgcn_mfma_f32_16x16x32_f16(af[mf], bf[nf], acc[mf][nf], 0, 0, 0); }

  STAGE(0, 0);
  STAGE(1, 1);
  int cur = 0, n2 = 2;
  for (int kk = 0; kk < 30; ++kk) {
    STAGE(kk + 2, n2);
    asm volatile("s_waitcnt vmcnt(8)" ::: "memory");  // tile kk's 4 loads done
    __builtin_amdgcn_s_barrier();
    __builtin_amdgcn_sched_barrier(0);
    COMPUTE(cur);
    __builtin_amdgcn_s_barrier();                     // all reads of cur done
    cur = (cur == 2) ? 0 : cur + 1;
    n2  = (n2  == 2) ? 0 : n2  + 1;
  }
  asm volatile("s_waitcnt vmcnt(4)" ::: "memory");
  __builtin_amdgcn_s_barrier();
  __builtin_amdgcn_sched_barrier(0);
  COMPUTE(cur);
  __builtin_amdgcn_s_barrier();
  cur = (cur == 2) ? 0 : cur + 1;
  asm volatile("s_waitcnt vmcnt(0)" ::: "memory");
  __builtin_amdgcn_s_barrier();
  __builtin_amdgcn_sched_barrier(0);
  COMPUTE(cur);
  #undef STAGE
  #undef COMPUTE

  int slot = by * 2 + wn;          // 0..15, deterministic partials (no atomics)
  #pragma unroll
  for (int mf = 0; mf < 4; ++mf)
    #pragma unroll
    for (int j = 0; j < 4; ++j) {
      float s = 0.f, q = 0.f;
      #pragma unroll
      for (int nf = 0; nf < 4; ++nf) { float v = acc[mf][nf][j]; s += v; q += v * v; }
      #pragma unroll
      for (int off = 1; off < 16; off <<= 1) { s += __shfl_xor(s, off, 64); q += __shfl_xor(q, off, 64); }
      if (l15 == 0) {
        int m = m0 + wm * 64 + mf * 16 + h * 4 + j;
        rs16[(size_t)slot * 16384 + m] = s;
        rq16[(size_t)slot * 16384 + m] = q;
      }
    }
}

// ---------------- K7: sim[i][c] — one block per (i,c), lane per word (compact rows) ----------------
__global__ __launch_bounds__(64) void k_final(const float* __restrict__ rs16,
    const float* __restrict__ rq16, const int* __restrict__ lens,
    const int* __restrict__ pfx, float* __restrict__ out) {
  int b = blockIdx.x;              // 0..511 = i*32 + c
  int c = b & 31;
  int l = threadIdx.x;             // 0..63, words are 0..31
  int len = lens[c];
  float sv = 0.f;
  if (l < len) {
    int i = b >> 5;
    int row = (pfx[c] + l) * 16 + i;
    float rs = 0.f, rq = 0.f;
    #pragma unroll
    for (int s = 0; s < 16; ++s) {
      rs += rs16[(size_t)s * 16384 + row];
      rq += rq16[(size_t)s * 16384 + row];
    }
    sv = rs / (sqrtf(rq) + EPSF);
  }
  #pragma unroll
  for (int off = 32; off > 0; off >>= 1) sv += __shfl_down(sv, off, 64);
  if (l == 0) out[b] = sv / (float)len;
}

extern "C" void kernel_launch(void* const* d_in, const int* in_sizes, int n_in,
                              void* d_out, int out_size, void* d_ws, size_t ws_size,
                              hipStream_t stream) {
  const float* img  = (const float*)d_in[0];   // (16,36,1024)
  const float* cap  = (const float*)d_in[1];   // (32,32,1024)
  const float* W    = (const float*)d_in[2];   // (1024,1024)
  const float* simw = (const float*)d_in[3];   // (1,1024)
  const float* tsw  = (const float*)d_in[4];   // (1,1)
  const float* tlw  = (const float*)d_in[5];   // (1,1)
  const int*   lens = (const int*)d_in[6];     // (32,)
  float* out = (float*)d_out;

  char* wsB = (char*)d_ws;
  if (ws_size < 51122176) return;   // needs ~48.8 MB scratch
  float* Dlw   = (float*)(wsB + 0);            // 4 MB (dead after k_diag_part -> reused)
  f16*   DlwH  = (f16*)  (wsB + 4194304);      // 2 MB
  float* diag  = (float*)(wsB + 6291456);      // 4 KB
  f16*   capH  = (f16*)  (wsB + 6295552);      // 2 MB
  f16*   imgdH = (f16*)  (wsB + 8392704);      // 1.5 MB (768 rows: 48/img, zero-padded)
  float* dpart = (float*)(wsB + 9965568);      // 64 KB (in old qk region)
  float* pw    = (float*)(wsB + 13111296);     // 2.25 MB (16 x 1024 x 36)
  f16*   slc   = (f16*)  (wsB + 15470592);     // 32 MB (compact rows x 1024)
  float* rs16  = (float*)(wsB + 49025024);     // 1 MB
  float* rq16  = (float*)(wsB + 50073600);     // 1 MB
  f16*   imgH  = (f16*)Dlw;                     // 1.18 MB at +0 (Dlw dead after k_diag_part)
  int*   mp    = (int*)(wsB + 2097152);         // in dead Dlw region, past imgH
  int*   pfx   = (int*)(wsB + 2097152 + 256);   // 33 ints

  k_dlw<<<1024, 256, 0, stream>>>(W, simw, tlw, Dlw, DlwH);
  k_diag_part<<<dim3(4, 16), 256, 0, stream>>>(Dlw, dpart);
  k_diag2p<<<5, 256, 0, stream>>>(dpart, lens, diag, pfx, mp);  // Dlw region now dead
  k_prep<<<2368, 256, 0, stream>>>(cap, img, diag, capH, imgH, imgdH);
  k_qk<<<dim3(16, 16), 256, 0, stream>>>(capH, imgdH, lens, tsw, pw);
  k_ctx<<<dim3(32, 16), 256, 0, stream>>>(pw, imgH, cap, lens, pfx, slc);
  k_gemm<<<dim3(128, 8), 256, 0, stream>>>(slc, DlwH, mp, rs16, rq16);
  k_final<<<512, 64, 0, stream>>>(rs16, rq16, lens, pfx, out);
}

// Round 13
// 102.065 us; speedup vs baseline: 1.1271x; 1.0137x over previous
//
#include <hip/hip_runtime.h>
#include <hip/hip_bf16.h>

#define I_N 16
#define C_N 32
#define L_N 32
#define R_N 36
#define D_N 1024
#define EPSF 1e-8f

typedef _Float16 f16;
typedef __attribute__((ext_vector_type(8))) _Float16 half8;
typedef __attribute__((ext_vector_type(4))) float floatx4;

// async global->LDS, 16B per lane; LDS dest = wave-uniform base + lane*16
__device__ __forceinline__ void gl16(const f16* g, f16* l) {
  __builtin_amdgcn_global_load_lds(
      (const __attribute__((address_space(1))) void*)g,
      (__attribute__((address_space(3))) void*)l, 16, 0, 0);
}

// fast stable tanh via v_exp: tanh(x) = sign(x) * (1-e^{-2|x|})/(1+e^{-2|x|})
__device__ __forceinline__ float fast_tanh(float x) {
  float q = __expf(-2.f * fabsf(x));
  float t = (1.f - q) / (1.f + q);
  return (x >= 0.f) ? t : -t;
}

// ---------------- block-wide sum over 256 threads ----------------
__device__ __forceinline__ float blk_sum_256(float v, float* red) {
  #pragma unroll
  for (int off = 32; off > 0; off >>= 1) v += __shfl_down(v, off, 64);
  int wid = threadIdx.x >> 6;
  if ((threadIdx.x & 63) == 0) red[wid] = v;
  __syncthreads();
  float s = red[0] + red[1] + red[2] + red[3];
  __syncthreads();
  return s;
}

// ---------------- K1: Dlw rows + f16 copy | imgP = f16(img) padded 36->48 ----------------
// blocks 0..1023: Dlw row; blocks 1024..1791: imgP row (independent work, co-scheduled)
__global__ __launch_bounds__(256) void k_dlw(const float* __restrict__ W,
    const float* __restrict__ simw, const float* __restrict__ tlw,
    const float* __restrict__ img,
    float* __restrict__ Dlw, f16* __restrict__ DlwH, f16* __restrict__ imgP) {
  int bid = blockIdx.x, tid = threadIdx.x;
  if (bid >= 1024) {                 // ---- imgP branch ----
    int row = bid - 1024;            // 0..767 = i*48 + r
    int i = row / 48, r = row % 48;
    size_t dst = (size_t)row * D_N;
    if (r < R_N) {
      size_t src = ((size_t)i * R_N + r) * D_N;
      #pragma unroll
      for (int k = 0; k < 4; ++k) {
        int j = tid + k * 256;
        imgP[dst + j] = (f16)img[src + j];
      }
    } else {
      #pragma unroll
      for (int k = 0; k < 4; ++k) {
        int j = tid + k * 256;
        imgP[dst + j] = (f16)0.f;
      }
    }
    return;
  }
  // ---- Dlw branch (idx==identity -> weights = sigmoid(W)) ----
  int row = bid;
  __shared__ float red[4];
  const float* Wr = W + (size_t)row * D_N;
  float w[4]; float p = 0.f;
  #pragma unroll
  for (int k = 0; k < 4; ++k) {
    int j = tid + k * 256;
    float x = Wr[j];
    w[k] = 1.f / (1.f + __expf(-x));
    p += w[k];
  }
  float S = blk_sum_256(p, red);
  float mean = S * (1.f / 1024.f);
  p = 0.f;
  #pragma unroll
  for (int k = 0; k < 4; ++k) { float d = w[k] - mean; p += d * d; }
  float S2 = blk_sum_256(p, red);
  float stdv = sqrtf(S2 * (1.f / 1023.f));   // ddof=1
  float thres = mean + simw[row] * stdv;
  float eT = __expf(tlw[0]);
  float mw[4]; p = 0.f;
  #pragma unroll
  for (int k = 0; k < 4; ++k) {
    float val = eT * (w[k] - thres);
    float y = __expf(val);                 // >= 0; inf ok (tanh->1)
    float q = __expf(-2.f * y);
    float mp = (1.f - q) / (1.f + q);      // tanh(y), y>=0
    mw[k] = mp * w[k];
    p += mw[k] * mw[k];
  }
  float S3 = blk_sum_256(p, red);
  float inv = 1.f / (sqrtf(S3) + EPSF);
  #pragma unroll
  for (int k = 0; k < 4; ++k) {
    int j = tid + k * 256;
    float v = mw[k] * inv;
    Dlw[(size_t)row * D_N + j] = v;
    DlwH[(size_t)row * D_N + j] = (f16)v;
  }
}

// ---------------- K2: dpart strips + prefix scan of cap_lens ----------------
// blocks 0..63: dpart[p][cols]; block 64: pfx/mp (pfx lives OUTSIDE Dlw region!)
__global__ __launch_bounds__(256) void k_dpp(const float* __restrict__ Dlw,
    const int* __restrict__ lens, float* __restrict__ dpart,
    int* __restrict__ pfx, int* __restrict__ mp) {
  int bid = blockIdx.x;
  if (bid < 64) {
    int p = bid >> 2;                   // 0..15
    int col = (bid & 3) * 256 + threadIdx.x;
    float s = 0.f;
    #pragma unroll 8
    for (int r = p * 64; r < p * 64 + 64; ++r) s += Dlw[(size_t)r * D_N + col];
    dpart[(size_t)p * D_N + col] = s;
  } else if (threadIdx.x < 64) {
    int l = threadIdx.x;
    int v = (l < 32) ? lens[l] : 0;
    int s = v;
    #pragma unroll
    for (int off = 1; off < 32; off <<= 1) {
      int t = __shfl_up(s, off, 64);
      if (l >= off) s += t;
    }
    if (l < 32) pfx[l] = s - v;          // exclusive prefix
    if (l == 31) { pfx[32] = s; mp[0] = s * 16; }
  }
}

// ---------------- K3: capD = f16(cap * diag), diag recomputed from dpart in LDS ----------------
__global__ __launch_bounds__(256) void k_capd(const float* __restrict__ dpart,
    const float* __restrict__ cap, f16* __restrict__ capD) {
  __shared__ float dg[D_N];
  int tid = threadIdx.x;
  #pragma unroll
  for (int k = 0; k < 4; ++k) {
    int col = tid + k * 256;
    float s = 0.f;
    #pragma unroll
    for (int p = 0; p < 16; ++p) s += dpart[(size_t)p * D_N + col];
    dg[col] = s;
  }
  __syncthreads();
  size_t base = (size_t)blockIdx.x * D_N;
  #pragma unroll
  for (int k = 0; k < 4; ++k) {
    int j = tid + k * 256;
    capD[base + j] = (f16)(cap[base + j] * dg[j]);
  }
}

// ---------------- K4: qk MFMA + FUSED attn epilogue -> pw ----------------
// A = capD (cap*diag), B = imgP (plain img, padded 48). Product unchanged.
__global__ __launch_bounds__(256) void k_qk(const f16* __restrict__ A,
    const f16* __restrict__ B, const int* __restrict__ lens,
    const float* __restrict__ tsw, float* __restrict__ pw) {
  int mt = blockIdx.x;             // 0..15
  int i  = blockIdx.y;             // 0..15
  int tid = threadIdx.x;
  int w = tid >> 6, lane = tid & 63;
  int l15 = lane & 15, h = lane >> 4;
  __shared__ __align__(16) f16 Als[64 * 32];
  __shared__ __align__(16) f16 Bls[48 * 32];
  __shared__ float att[64][49];    // +1 pad breaks column-sum conflicts
  __shared__ float cn[2][R_N];
  floatx4 acc[3];
  #pragma unroll
  for (int nf = 0; nf < 3; ++nf) acc[nf] = (floatx4)0.f;
  int arow = tid >> 2;             // 0..63
  int u = tid & 3;                 // 16B unit within row
  int vf = (u | ((arow & 1) << 2)) ^ ((arow >> 1) & 7);
  int wofs = (((arow & 62) | (vf >> 2)) * 32) + (vf & 3) * 8;
  const f16* Ag = A + (size_t)(mt * 64 + arow) * D_N + u * 8;
  const f16* Bg = B + (size_t)(i * 48 + arow) * D_N + u * 8;
  int v2 = (h | ((l15 & 1) << 2)) ^ ((l15 >> 1) & 7);
  int rbit = (v2 >> 2) & 1;
  int pun = (v2 & 3) * 8;
  int aoff = (w * 16 + (l15 & 14) + rbit) * 32 + pun;
  int boff[3];
  #pragma unroll
  for (int nf = 0; nf < 3; ++nf) boff[nf] = (nf * 16 + (l15 & 14) + rbit) * 32 + pun;
  for (int kk = 0; kk < D_N; kk += 32) {
    *(float4*)(&Als[wofs]) = *(const float4*)(Ag + kk);
    if (tid < 192) *(float4*)(&Bls[wofs]) = *(const float4*)(Bg + kk);
    __syncthreads();
    half8 a = *(const half8*)(&Als[aoff]);
    #pragma unroll
    for (int nf = 0; nf < 3; ++nf) {
      half8 b = *(const half8*)(&Bls[boff[nf]]);
      acc[nf] = __builtin_amdgcn_mfma_f32_16x16x32_f16(a, b, acc[nf], 0, 0, 0);
    }
    __syncthreads();
  }
  // ---- fused epilogue ----
  int len0 = lens[mt * 2], len1 = lens[mt * 2 + 1];
  #pragma unroll
  for (int nf = 0; nf < 3; ++nf)
    #pragma unroll
    for (int j = 0; j < 4; ++j) {
      int ml = w * 16 + h * 4 + j;           // 0..63
      int n = nf * 16 + l15;                 // 0..47
      float t = fast_tanh(acc[nf][j]);
      float v = (t >= 0.f) ? t : 0.1f * t;   // LeakyReLU(0.1)
      int len = (ml >= 32) ? len1 : len0;
      if ((ml & 31) >= len || n >= R_N) v = 0.f;   // word mask + col pad
      att[ml][n] = v;
    }
  __syncthreads();
  for (int e = tid; e < 2 * R_N; e += 256) {       // word-dim l2norm, per caption
    int cc = e / R_N, r = e % R_N;
    float s = 0.f;
    #pragma unroll
    for (int l = 0; l < 32; ++l) { float a = att[cc * 32 + l][r]; s += a * a; }
    cn[cc][r] = sqrtf(s) + EPSF;
  }
  __syncthreads();
  if (tid < 64) {                                  // softmax over regions, per row
    int cc = tid >> 5, l = tid & 31;
    float smooth = __expf(tsw[0]);
    float mx = -3.4e38f;
    #pragma unroll
    for (int r = 0; r < R_N; ++r) {
      float z = att[tid][r] / cn[cc][r] * smooth;
      att[tid][r] = z;
      mx = fmaxf(mx, z);
    }
    float se = 0.f;
    #pragma unroll
    for (int r = 0; r < R_N; ++r) {
      float e2 = __expf(att[tid][r] - mx);
      att[tid][r] = e2;
      se += e2;
    }
    float inv = 1.f / se;
    float* dst = pw + ((size_t)i * 1024 + (mt * 2 + cc) * 32 + l) * R_N;
    #pragma unroll
    for (int r = 0; r < R_N; ++r) dst[r] = att[tid][r] * inv;
  }
}

// ---------------- K5: ctx = attn @ img[i]; l2norm; * cap -> COMPACT sim_loc (f16) ----------------
// One block per (caption, image): stage img[i] ONCE (72 KB), two 16-row sub-passes.
__global__ __launch_bounds__(256) void k_ctx(const float* __restrict__ pw,
    const f16* __restrict__ imgP, const float* __restrict__ cap,
    const int* __restrict__ lens, const int* __restrict__ pfx,
    f16* __restrict__ slc) {
  int c  = blockIdx.x;             // 0..31 caption
  int i  = blockIdx.y;             // 0..15 image
  int tid = threadIdx.x;
  int w = tid >> 6;                // wave id
  int cg = tid & 63;
  int len = lens[c];
  int pf = pfx[c];
  __shared__ float pA[32][R_N];
  __shared__ __align__(16) f16 rows[R_N][1024];   // 72 KB
  for (int e = tid; e < 32 * R_N; e += 256) {
    int rr = e / R_N, r = e % R_N;
    pA[rr][r] = pw[((size_t)i * 1024 + c * 32 + rr) * R_N + r];
  }
  const f16* base = imgP + (size_t)i * 48 * D_N;   // padded stride, rows 0..35 used
  #pragma unroll
  for (int t = 0; t < 9; ++t) {
    int rr = w * 9 + t;
    const f16* src = base + (size_t)rr * D_N + cg * 8;
    gl16(src,       &rows[rr][0]);
    gl16(src + 512, &rows[rr][512]);
  }
  __syncthreads();                 // drains vmcnt + lgkm once
  int d0 = cg * 8, d1 = 512 + cg * 8;
  #pragma unroll
  for (int sub = 0; sub < 2; ++sub) {
    float acc[4][16];
    #pragma unroll
    for (int j = 0; j < 4; ++j)
      #pragma unroll
      for (int q = 0; q < 16; ++q) acc[j][q] = 0.f;
    for (int k = 0; k < R_N; ++k) {
      half8 h0 = *(const half8*)(&rows[k][d0]);
      half8 h1 = *(const half8*)(&rows[k][d1]);
      float bv[16];
      #pragma unroll
      for (int q = 0; q < 8; ++q) { bv[q] = (float)h0[q]; bv[8 + q] = (float)h1[q]; }
      #pragma unroll
      for (int j = 0; j < 4; ++j) {
        float a = pA[sub * 16 + w * 4 + j][k];
        #pragma unroll
        for (int q = 0; q < 16; ++q) acc[j][q] += a * bv[q];
      }
    }
    #pragma unroll
    for (int j = 0; j < 4; ++j) {
      int l = sub * 16 + w * 4 + j;      // word index 0..31
      float ss = 0.f;
      #pragma unroll
      for (int q = 0; q < 16; ++q) ss += acc[j][q] * acc[j][q];
      #pragma unroll
      for (int off = 1; off < 64; off <<= 1) ss += __shfl_xor(ss, off, 64);
      if (l < len) {
        float inv = 1.f / (sqrtf(ss) + EPSF);
        const float* capr = cap + ((size_t)c * L_N + l) * D_N;
        float4 c0 = *(const float4*)(capr + d0);
        float4 c1 = *(const float4*)(capr + d0 + 4);
        float4 c2 = *(const float4*)(capr + d1);
        float4 c3 = *(const float4*)(capr + d1 + 4);
        float cv[16] = {c0.x,c0.y,c0.z,c0.w, c1.x,c1.y,c1.z,c1.w,
                        c2.x,c2.y,c2.z,c2.w, c3.x,c3.y,c3.z,c3.w};
        union { f16 h[16]; float4 f4[2]; } u;
        #pragma unroll
        for (int q = 0; q < 16; ++q) u.h[q] = (f16)(acc[j][q] * inv * cv[q]);
        f16* dst = slc + ((size_t)((pf + l) * 16 + i)) * D_N;
        *(float4*)(dst + d0) = u.f4[0];
        *(float4*)(dst + d1) = u.f4[1];
      }
    }
  }
}

// ---------------- K6: big GEMM (compacted M) f16 MFMA, fused rowsum/rowsumsq ----------------
// 128x128 tile, BK=32, 4 waves 2x2. TRIPLE-buffered LDS, depth-2 prefetch via
// global_load_lds + inverse-swizzled global source + swizzled ds_read offsets.
// FROZEN R9/R11 sync structure (depth-1 regressed in R10; 4-buf would break
// single-round residency at 576 blocks).
__global__ __launch_bounds__(256) void k_gemm(const f16* __restrict__ A,
    const f16* __restrict__ B, const int* __restrict__ mp,
    float* __restrict__ rs16, float* __restrict__ rq16) {
  int bx = blockIdx.x, by = blockIdx.y;
  int Mp = mp[0];
  int m0 = bx * 128, n0 = by * 128;
  if (m0 >= Mp) return;            // uniform per block; compacted tail
  int tid = threadIdx.x;
  int w = tid >> 6, lane = tid & 63;
  int l15 = lane & 15, h = lane >> 4;
  int wm = w >> 1, wn = w & 1;
  __shared__ __align__(16) f16 AB[3][2][128 * 32];   // 48 KB
  floatx4 acc[4][4];
  #pragma unroll
  for (int mf = 0; mf < 4; ++mf)
    #pragma unroll
    for (int nf = 0; nf < 4; ++nf) acc[mf][nf] = (floatx4)0.f;

  // ---- staging: lane's linear LDS slot (r_p,u_p) must receive logical (r_l,u_l)
  int r_p = lane >> 2, u_p = lane & 3;
  int sw = (r_p >> 1) & 7;
  int val = (u_p | ((r_p & 1) << 2)) ^ sw;
  int r_l = (r_p & 14) | (val >> 2);
  int u_l = val & 3;
  const f16* As0 = A + (size_t)(m0 + w * 32 +  0 + r_l) * D_N + u_l * 8;
  const f16* As1 = A + (size_t)(m0 + w * 32 + 16 + r_l) * D_N + u_l * 8;
  const f16* Bs0 = B + (size_t)(n0 + w * 32 +  0 + r_l) * D_N + u_l * 8;
  const f16* Bs1 = B + (size_t)(n0 + w * 32 + 16 + r_l) * D_N + u_l * 8;

  // ---- fragment reads: physical (swizzled) offsets, loop-invariant
  int v2 = (h | ((l15 & 1) << 2)) ^ ((l15 >> 1) & 7);
  int rbit = (v2 >> 2) & 1;
  int pun = (v2 & 3) * 8;
  int aoff[4], boff[4];
  #pragma unroll
  for (int f = 0; f < 4; ++f) {
    aoff[f] = (wm * 64 + f * 16 + (l15 & 14) + rbit) * 32 + pun;
    boff[f] = (wn * 64 + f * 16 + (l15 & 14) + rbit) * 32 + pun;
  }

  #define STAGE(kt, b) { \
    int kof = (kt) * 32; \
    gl16(As0 + kof, &AB[b][0][(w * 32 +  0) * 32]); \
    gl16(As1 + kof, &AB[b][0][(w * 32 + 16) * 32]); \
    gl16(Bs0 + kof, &AB[b][1][(w * 32 +  0) * 32]); \
    gl16(Bs1 + kof, &AB[b][1][(w * 32 + 16) * 32]); }

  #define COMPUTE(b) { \
    half8 af[4], bf[4]; \
    _Pragma("unroll") for (int f = 0; f < 4; ++f) af[f] = *(const half8*)(&AB[b][0][aoff[f]]); \
    _Pragma("unroll") for (int f = 0; f < 4; ++f) bf[f] = *(const half8*)(&AB[b][1][boff[f]]); \
    _Pragma("unroll") for (int mf = 0; mf < 4; ++mf) \
      _Pragma("unroll") for (int nf = 0; nf < 4; ++nf) \
        acc[mf][nf] = __builtin_amdgcn_mfma_f32_16x16x32_f16(af[mf], bf[nf], acc[mf][nf], 0, 0, 0); }

  STAGE(0, 0);
  STAGE(1, 1);
  int cur = 0, n2 = 2;
  for (int kk = 0; kk < 30; ++kk) {
    STAGE(kk + 2, n2);
    asm volatile("s_waitcnt vmcnt(8)" ::: "memory");  // tile kk's 4 loads done
    __builtin_amdgcn_s_barrier();
    __builtin_amdgcn_sched_barrier(0);
    COMPUTE(cur);
    __builtin_amdgcn_s_barrier();                     // all reads of cur done
    cur = (cur == 2) ? 0 : cur + 1;
    n2  = (n2  == 2) ? 0 : n2  + 1;
  }
  asm volatile("s_waitcnt vmcnt(4)" ::: "memory");
  __builtin_amdgcn_s_barrier();
  __builtin_amdgcn_sched_barrier(0);
  COMPUTE(cur);
  __builtin_amdgcn_s_barrier();
  cur = (cur == 2) ? 0 : cur + 1;
  asm volatile("s_waitcnt vmcnt(0)" ::: "memory");
  __builtin_amdgcn_s_barrier();
  __builtin_amdgcn_sched_barrier(0);
  COMPUTE(cur);
  #undef STAGE
  #undef COMPUTE

  int slot = by * 2 + wn;          // 0..15, deterministic partials (no atomics)
  #pragma unroll
  for (int mf = 0; mf < 4; ++mf)
    #pragma unroll
    for (int j = 0; j < 4; ++j) {
      float s = 0.f, q = 0.f;
      #pragma unroll
      for (int nf = 0; nf < 4; ++nf) { float v = acc[mf][nf][j]; s += v; q += v * v; }
      #pragma unroll
      for (int off = 1; off < 16; off <<= 1) { s += __shfl_xor(s, off, 64); q += __shfl_xor(q, off, 64); }
      if (l15 == 0) {
        int m = m0 + wm * 64 + mf * 16 + h * 4 + j;
        rs16[(size_t)slot * 16384 + m] = s;
        rq16[(size_t)slot * 16384 + m] = q;
      }
    }
}

// ---------------- K7: sim[i][c] — one block per (i,c), lane per word (compact rows) ----------------
__global__ __launch_bounds__(64) void k_final(const float* __restrict__ rs16,
    const float* __restrict__ rq16, const int* __restrict__ lens,
    const int* __restrict__ pfx, float* __restrict__ out) {
  int b = blockIdx.x;              // 0..511 = i*32 + c
  int c = b & 31;
  int l = threadIdx.x;             // 0..63, words are 0..31
  int len = lens[c];
  float sv = 0.f;
  if (l < len) {
    int i = b >> 5;
    int row = (pfx[c] + l) * 16 + i;
    float rs = 0.f, rq = 0.f;
    #pragma unroll
    for (int s = 0; s < 16; ++s) {
      rs += rs16[(size_t)s * 16384 + row];
      rq += rq16[(size_t)s * 16384 + row];
    }
    sv = rs / (sqrtf(rq) + EPSF);
  }
  #pragma unroll
  for (int off = 32; off > 0; off >>= 1) sv += __shfl_down(sv, off, 64);
  if (l == 0) out[b] = sv / (float)len;
}

extern "C" void kernel_launch(void* const* d_in, const int* in_sizes, int n_in,
                              void* d_out, int out_size, void* d_ws, size_t ws_size,
                              hipStream_t stream) {
  const float* img  = (const float*)d_in[0];   // (16,36,1024)
  const float* cap  = (const float*)d_in[1];   // (32,32,1024)
  const float* W    = (const float*)d_in[2];   // (1024,1024)
  const float* simw = (const float*)d_in[3];   // (1,1024)
  const float* tsw  = (const float*)d_in[4];   // (1,1)
  const float* tlw  = (const float*)d_in[5];   // (1,1)
  const int*   lens = (const int*)d_in[6];     // (32,)
  float* out = (float*)d_out;

  char* wsB = (char*)d_ws;
  if (ws_size < 51122176) return;   // needs ~48.8 MB scratch
  float* Dlw   = (float*)(wsB + 0);            // 4 MB (read by k_dpp, then dead)
  f16*   DlwH  = (f16*)  (wsB + 4194304);      // 2 MB
  f16*   capD  = (f16*)  (wsB + 6295552);      // 2 MB (cap * diag, f16)
  f16*   imgP  = (f16*)  (wsB + 8392704);      // 1.5 MB (768 rows: 48/img, zero-padded)
  float* dpart = (float*)(wsB + 9965568);      // 64 KB
  int*   mp    = (int*)  (wsB + 10031104);     // outside live Dlw region!
  int*   pfx   = (int*)  (wsB + 10031360);     // 33 ints
  float* pw    = (float*)(wsB + 13111296);     // 2.25 MB (16 x 1024 x 36)
  f16*   slc   = (f16*)  (wsB + 15470592);     // 32 MB (compact rows x 1024)
  float* rs16  = (float*)(wsB + 49025024);     // 1 MB
  float* rq16  = (float*)(wsB + 50073600);     // 1 MB

  k_dlw<<<1792, 256, 0, stream>>>(W, simw, tlw, img, Dlw, DlwH, imgP);
  k_dpp<<<65, 256, 0, stream>>>(Dlw, lens, dpart, pfx, mp);
  k_capd<<<1024, 256, 0, stream>>>(dpart, cap, capD);
  k_qk<<<dim3(16, 16), 256, 0, stream>>>(capD, imgP, lens, tsw, pw);
  k_ctx<<<dim3(32, 16), 256, 0, stream>>>(pw, imgP, cap, lens, pfx, slc);
  k_gemm<<<dim3(128, 8), 256, 0, stream>>>(slc, DlwH, mp, rs16, rq16);
  k_final<<<512, 64, 0, stream>>>(rs16, rq16, lens, pfx, out);
}